// Round 1
// baseline (242.187 us; speedup 1.0000x reference)
//
#include <hip/hip_runtime.h>

// Izhikevich neuron scan. x: [B=16, C=64, N=1024, T=32] f32, T contiguous.
// 1M independent neurons, 32-step sequential recurrence each.
//
// R3 post-mortem: single-wave blocks removed the barrier convoy, but each
// block was ONE tile: 8 loads issued, then the wave went VMEM-silent through
// transpose+compute+store (~15 us residency for 16 KB of traffic). Chip-wide
// outstanding bytes collapsed => latency-bound at 2.35 TB/s / 29% of peak,
// VALUBusy 18%, occupancy 35%.
//
// R4: multi-tile blocks + depth-1 software prefetch.
//  - Each single-wave block processes NT=4 consecutive 64-neuron tiles.
//  - Loop: transpose-write tile i -> issue tile i+1's 8 global loads into
//    separate regs (chn, avoids WAR on in-flight ds_write sources) ->
//    compute + store tile i. Loads stay in flight under ~2000 cycles of
//    LDS+VALU work => every wave keeps ~8 KB outstanding continuously.
//  - Grid = 4096 = 16 blocks/CU: whole grid resident (LDS cap 17), no
//    dispatch churn, no tail.
//  - NO __syncthreads(): its semantics force s_waitcnt vmcnt(0), which would
//    drain the prefetch each iteration. Single-wave DS ops complete in order,
//    so explicit lgkmcnt(0) at the two transpose boundaries is sufficient
//    (that is all the elided barrier gave us before, minus the vmcnt drain).
//
// Numerics: bit-exact f32 replication of the reference (contract off,
// left-assoc order, literal spike-blend). LDS round-trip preserves bits.

#define T_STEPS 32
#define TPB 64          // one wave per block: no barriers, no convoy
#define ROW 36          // floats; 144 B rows, 16B-aligned, conflict-free (2-way)
#define NT 4            // tiles (of 64 neurons) per block, software-pipelined

__global__ __launch_bounds__(TPB) void izhikevich_kernel(
    const float* __restrict__ x,
    const float* __restrict__ pa,
    const float* __restrict__ pb,
    const float* __restrict__ pc,
    const float* __restrict__ pd,
    float* __restrict__ out)
{
#pragma clang fp contract(off)
    __shared__ float lds[TPB * ROW];            // 9216 B -> 17 blocks/CU cap

    const int t = threadIdx.x;
    const size_t tile_elems = (size_t)TPB * T_STEPS;            // 2048 floats
    const size_t base0 = (size_t)blockIdx.x * (NT * tile_elems);

    const float a = pa[0];
    const float b = pb[0];
    const float c = pc[0];
    const float d = pd[0];

    // ---- Prologue: coalesced loads for tile 0 (8 KB/wave in flight) ------
    float4 ch[8];
    {
        const float4* __restrict__ xin = reinterpret_cast<const float4*>(x + base0);
#pragma unroll
        for (int k = 0; k < 8; ++k) ch[k] = xin[k * TPB + t];
    }

#pragma unroll
    for (int it = 0; it < NT; ++it) {
        // ---- Phase 1: transposing scatter into LDS (b128, 2-way = free) --
        // float4 #(k*64+t) holds neuron ng = k*8 + t/8, times (t%8)*4 .. +3.
        // (compiler inserts the counted vmcnt wait for ch here)
#pragma unroll
        for (int k = 0; k < 8; ++k) {
            const int ng = k * 8 + (t >> 3);
            const int tg = (t & 7) * 4;
            *reinterpret_cast<float4*>(&lds[ng * ROW + tg]) = ch[k];
        }

        // ---- Phase 2: PREFETCH tile it+1 — rides under compute below -----
        float4 chn[8];
        if (it + 1 < NT) {
            const float4* __restrict__ xin =
                reinterpret_cast<const float4*>(x + base0 + (size_t)(it + 1) * tile_elems);
#pragma unroll
            for (int k = 0; k < 8; ++k) chn[k] = xin[k * TPB + t];
        }

        // single-wave "barrier": DS completes in order; just drain lgkm.
        asm volatile("s_waitcnt lgkmcnt(0)" ::: "memory");

        // ---- Phase 3: own-row gather (b128) ------------------------------
        float xs[T_STEPS];
#pragma unroll
        for (int j = 0; j < 8; ++j)
            *reinterpret_cast<float4*>(&xs[j * 4]) =
                *reinterpret_cast<const float4*>(&lds[t * ROW + j * 4]);

        // ---- Phase 4: recurrence (bit-exact), spikes back to own row -----
        float v = 0.0f;
        float u = 0.0f;
#pragma unroll
        for (int j = 0; j < 8; ++j) {
            float4 sp;
            float* sf = reinterpret_cast<float*>(&sp);
#pragma unroll
            for (int i = 0; i < 4; ++i) {
                const float xt = xs[j * 4 + i];
                // dv = 0.04*v*v + 5.0*v + 140.0 - u + x_t (left-assoc, no fma)
                const float t1 = (0.04f * v) * v;
                const float t2 = 5.0f * v;
                const float dv = (((t1 + t2) + 140.0f) - u) + xt;
                v = v + dv;                          // DT = 1.0 exact
                const float du = a * ((b * v) - u);
                u = u + du;
                const float spike = (v >= 30.0f) ? 1.0f : 0.0f;
                const float oms = 1.0f - spike;
                v = (v * oms) + (c * spike);         // exact for spike in {0,1}
                u = u + (d * spike);
                sf[i] = spike;
            }
            *reinterpret_cast<float4*>(&lds[t * ROW + j * 4]) = sp;
        }

        asm volatile("s_waitcnt lgkmcnt(0)" ::: "memory");

        // ---- Phase 5: inverse transpose gather + coalesced stores --------
        {
            float4* __restrict__ op =
                reinterpret_cast<float4*>(out + base0 + (size_t)it * tile_elems);
#pragma unroll
            for (int k = 0; k < 8; ++k) {
                const int ng = k * 8 + (t >> 3);
                const int tg = (t & 7) * 4;
                const float4 o = *reinterpret_cast<const float4*>(&lds[ng * ROW + tg]);
                op[k * TPB + t] = o;
            }
        }

        // ---- rotate prefetch regs (renamed away by the full unroll) ------
        if (it + 1 < NT) {
#pragma unroll
            for (int k = 0; k < 8; ++k) ch[k] = chn[k];
        }
    }
}

extern "C" void kernel_launch(void* const* d_in, const int* in_sizes, int n_in,
                              void* d_out, int out_size, void* d_ws, size_t ws_size,
                              hipStream_t stream) {
    const float* x  = (const float*)d_in[0];
    const float* pa = (const float*)d_in[1];
    const float* pb = (const float*)d_in[2];
    const float* pc = (const float*)d_in[3];
    const float* pd = (const float*)d_in[4];
    float* out = (float*)d_out;

    const int n_neurons = in_sizes[0] / T_STEPS;   // 1,048,576
    const int grid = n_neurons / (TPB * NT);       // 4096 (exact)

    izhikevich_kernel<<<grid, TPB, 0, stream>>>(x, pa, pb, pc, pd, out);
}

// Round 3
// 241.154 us; speedup vs baseline: 1.0043x; 1.0043x over previous
//
#include <hip/hip_runtime.h>

// Izhikevich neuron scan. x: [B=16, C=64, N=1024, T=32] f32, T contiguous.
// 1M independent neurons, 32-step sequential recurrence each.
//
// R4 post-mortem: the asm("s_waitcnt lgkmcnt(0)" ::: "memory") barriers were
// poison — SIInsertWaitcnts conservatively emits s_waitcnt vmcnt(0) before
// inline asm with a memory clobber, draining the prefetch AND waiting on the
// previous tile's store-acks every iteration. VGPR_Count=44 proved the
// prefetch regs were never live across compute (backend sank the loads to
// their use). Result: R4 == R3 within noise, ~2 exposed latencies/tile.
//
// R5 (this version; R5a fixes compile: __builtin_nontemporal_store needs a
// NATIVE vector type, not HIP's float4 class -> ext_vector_type(4) alias):
//  - __builtin_amdgcn_sched_barrier(0): pure compile-time fence at the
//    cross-lane LDS hazard boundaries; generates NO waitcnt.
//  - __builtin_amdgcn_s_waitcnt(0xC07F): lgkmcnt(0) with vmcnt=63/expcnt=7
//    untouched — orders ds_write->ds_read without draining VMEM. Stores are
//    fire-and-forget; loads get counted vmcnt waits from the backend.
//  - Prefetch of tile i+1 issued FIRST each iteration, pinned above the
//    fence, so ~8 KB/wave stays in flight through transpose+compute+store.
//  - LDS row-gather merged into the compute loop (read j, compute 4 steps,
//    write spikes j): ~24 fewer live VGPRs so the pinned prefetch fits.
//  - Output via __builtin_nontemporal_store: never re-read; keeps L3 free
//    for the input across dispatches (signature: FETCH_SIZE drops).
//
// Numerics: bit-exact f32 replication of the reference (contract off,
// left-assoc order, literal spike-blend). LDS round-trip preserves bits.

#define T_STEPS 32
#define TPB 64          // one wave per block: no barriers, no convoy
#define ROW 36          // floats; 144 B rows, 16B-aligned, conflict-free
#define NT 4            // tiles (of 64 neurons) per block, software-pipelined

// s_waitcnt imm (gfx9 encoding): vmcnt=63 ([15:14],[3:0]), expcnt=7 ([6:4]),
// lgkmcnt=0 ([11:8])  ->  wait for LDS only, leave all VMEM in flight.
#define LGKM_ONLY 0xC07F

// Native clang vector: layout-identical to HIP float4, accepted by
// __builtin_nontemporal_store (HIP float4 is a class and is rejected).
typedef float vf4 __attribute__((ext_vector_type(4)));

__global__ __launch_bounds__(TPB) void izhikevich_kernel(
    const float* __restrict__ x,
    const float* __restrict__ pa,
    const float* __restrict__ pb,
    const float* __restrict__ pc,
    const float* __restrict__ pd,
    float* __restrict__ out)
{
#pragma clang fp contract(off)
    __shared__ float lds[TPB * ROW];            // 9216 B -> 17 blocks/CU cap

    const int t = threadIdx.x;
    const size_t tile_elems = (size_t)TPB * T_STEPS;            // 2048 floats
    const size_t base0 = (size_t)blockIdx.x * (NT * tile_elems);

    const float a = pa[0];
    const float b = pb[0];
    const float c = pc[0];
    const float d = pd[0];

    // ---- Prologue: coalesced loads for tile 0 (8 KB/wave in flight) ------
    vf4 ch[8];
    {
        const vf4* __restrict__ xin = reinterpret_cast<const vf4*>(x + base0);
#pragma unroll
        for (int k = 0; k < 8; ++k) ch[k] = xin[k * TPB + t];
    }

#pragma unroll
    for (int it = 0; it < NT; ++it) {
        // ---- Phase 0: PREFETCH tile it+1 FIRST — enters VMEM queue now,
        // pinned above the fence; retires under this tile's LDS+VALU work.
        vf4 chn[8];
        if (it + 1 < NT) {
            const vf4* __restrict__ xin = reinterpret_cast<const vf4*>(
                x + base0 + (size_t)(it + 1) * tile_elems);
#pragma unroll
            for (int k = 0; k < 8; ++k) chn[k] = xin[k * TPB + t];
        }
        __builtin_amdgcn_sched_barrier(0);

        // ---- Phase 1: transposing scatter into LDS (b128, 2-way = free) --
        // float4 #(k*64+t) holds neuron ng = k*8 + t/8, times (t%8)*4 .. +3.
        // Backend inserts a COUNTED vmcnt wait for ch here (chn stays out).
#pragma unroll
        for (int k = 0; k < 8; ++k) {
            const int ng = k * 8 + (t >> 3);
            const int tg = (t & 7) * 4;
            *reinterpret_cast<vf4*>(&lds[ng * ROW + tg]) = ch[k];
        }
        __builtin_amdgcn_s_waitcnt(LGKM_ONLY);   // LDS writes done; VMEM untouched
        __builtin_amdgcn_sched_barrier(0);       // cross-lane RAW fence

        // ---- Phase 2: own-row gather fused with recurrence (bit-exact) ---
        float v = 0.0f;
        float u = 0.0f;
#pragma unroll
        for (int j = 0; j < 8; ++j) {
            const vf4 xv = *reinterpret_cast<const vf4*>(&lds[t * ROW + j * 4]);
            vf4 sp;
#pragma unroll
            for (int i = 0; i < 4; ++i) {
                const float xt = xv[i];
                // dv = 0.04*v*v + 5.0*v + 140.0 - u + x_t (left-assoc, no fma)
                const float t1 = (0.04f * v) * v;
                const float t2 = 5.0f * v;
                const float dv = (((t1 + t2) + 140.0f) - u) + xt;
                v = v + dv;                          // DT = 1.0 exact
                const float du = a * ((b * v) - u);
                u = u + du;
                const float spike = (v >= 30.0f) ? 1.0f : 0.0f;
                const float oms = 1.0f - spike;
                v = (v * oms) + (c * spike);         // exact for spike in {0,1}
                u = u + (d * spike);
                sp[i] = spike;
            }
            // same row/col as the read above (same-lane MustAlias -> ordered)
            *reinterpret_cast<vf4*>(&lds[t * ROW + j * 4]) = sp;
        }
        __builtin_amdgcn_s_waitcnt(LGKM_ONLY);   // spike writes done
        __builtin_amdgcn_sched_barrier(0);       // cross-lane RAW fence

        // ---- Phase 3: inverse transpose gather + nontemporal stores ------
        {
            vf4* __restrict__ op =
                reinterpret_cast<vf4*>(out + base0 + (size_t)it * tile_elems);
#pragma unroll
            for (int k = 0; k < 8; ++k) {
                const int ng = k * 8 + (t >> 3);
                const int tg = (t & 7) * 4;
                const vf4 o = *reinterpret_cast<const vf4*>(&lds[ng * ROW + tg]);
                __builtin_nontemporal_store(o, op + k * TPB + t);
            }
        }
        __builtin_amdgcn_sched_barrier(0);       // WAR fence vs next phase 1

        // ---- rotate prefetch regs (renamed away by the full unroll) ------
        if (it + 1 < NT) {
#pragma unroll
            for (int k = 0; k < 8; ++k) ch[k] = chn[k];
        }
    }
}

extern "C" void kernel_launch(void* const* d_in, const int* in_sizes, int n_in,
                              void* d_out, int out_size, void* d_ws, size_t ws_size,
                              hipStream_t stream) {
    const float* x  = (const float*)d_in[0];
    const float* pa = (const float*)d_in[1];
    const float* pb = (const float*)d_in[2];
    const float* pc = (const float*)d_in[3];
    const float* pd = (const float*)d_in[4];
    float* out = (float*)d_out;

    const int n_neurons = in_sizes[0] / T_STEPS;   // 1,048,576
    const int grid = n_neurons / (TPB * NT);       // 4096 (exact)

    izhikevich_kernel<<<grid, TPB, 0, stream>>>(x, pa, pb, pc, pd, out);
}